// Round 11
// baseline (673.502 us; speedup 1.0000x reference)
//
#include <hip/hip_runtime.h>
#include <cstdint>
#include <cstddef>

#define CH 128
#define BM 64

typedef __attribute__((ext_vector_type(8))) short bf16x8;
typedef __attribute__((ext_vector_type(4))) float f32x4;

__device__ __forceinline__ unsigned short f2bf(float x){
    unsigned int u = __float_as_uint(x);
    u = (u + 0x7FFFu + ((u >> 16) & 1u)) >> 16;   // RNE
    return (unsigned short)u;
}
__device__ __forceinline__ float bf2f(unsigned short b){
    return __uint_as_float(((unsigned int)b) << 16);
}
__device__ __forceinline__ unsigned int pairadd_bf(unsigned int a, unsigned int b){
    float lo = bf2f((unsigned short)(a & 0xffff)) + bf2f((unsigned short)(b & 0xffff));
    float hi = bf2f((unsigned short)(a >> 16))    + bf2f((unsigned short)(b >> 16));
    return (unsigned int)f2bf(lo) | ((unsigned int)f2bf(hi) << 16);
}

// ---------------------------------------------------------------------------
// k0: transpose+convert weights to bf16 wT[mat][n][k]; zero sums[256*256].
// ---------------------------------------------------------------------------
__global__ __launch_bounds__(256) void k0_prep(
        const float* __restrict__ w_self, const float* __restrict__ w_h,
        const float* __restrict__ w_t, unsigned short* __restrict__ wT,
        float* __restrict__ sums){
    int t = blockIdx.x * 256 + threadIdx.x;
    if (t < 256*256) sums[t] = 0.f;
    if (t < 3*CH*CH){
        int mat = t / (CH*CH);
        int r = t - mat*(CH*CH);
        int k = r >> 7, n = r & 127;
        const float* w = (mat == 0) ? w_self : ((mat == 1) ? w_h : w_t);
        wT[mat*CH*CH + n*CH + k] = f2bf(w[k*CH + n]);
    }
}

// ---------------------------------------------------------------------------
// k1: H = x @ w_h, T = x @ w_t  (bf16 out, f32 MFMA accumulate). Proven R0-R10.
// ---------------------------------------------------------------------------
__global__ __launch_bounds__(512) void k1_ht(
        const float* __restrict__ x, const unsigned short* __restrict__ wT,
        unsigned short* __restrict__ H, unsigned short* __restrict__ T, int N){
    __shared__ __align__(16) unsigned char smem[98304];
    const int tid = threadIdx.x;
    const int m0 = blockIdx.x * 128;
    #pragma unroll
    for (int i = 0; i < 8; ++i){
        int g = tid + i*512;
        int row = g >> 5, col4 = (g & 31) * 4;
        int rg = m0 + row; rg = rg < N ? rg : N-1;
        float4 v = *(const float4*)(x + (size_t)rg*CH + col4);
        unsigned int lo = (unsigned int)f2bf(v.x) | ((unsigned int)f2bf(v.y) << 16);
        unsigned int hi = (unsigned int)f2bf(v.z) | ((unsigned int)f2bf(v.w) << 16);
        unsigned int b = ((unsigned int)(row*256 + col4*2)) ^ ((unsigned int)(row & 7) << 4);
        *(uint2*)(smem + b) = make_uint2(lo, hi);
    }
    #pragma unroll
    for (int m = 0; m < 2; ++m){
        const unsigned short* src = wT + (m+1)*CH*CH;
        unsigned char* dst = smem + 32768 + m*32768;
        #pragma unroll
        for (int i = 0; i < 4; ++i){
            int g = tid + i*512;
            int n = g >> 4, k8 = (g & 15) * 8;
            uint4 v = *(const uint4*)(src + n*CH + k8);
            unsigned int b = ((unsigned int)(n*256 + k8*2)) ^ ((unsigned int)(n & 7) << 4);
            *(uint4*)(dst + b) = v;
        }
    }
    __syncthreads();
    const int lane = tid & 63, wv = tid >> 6;
    const int lr = lane & 15, lg = lane >> 4;
    f32x4 accH[8], accT[8];
    #pragma unroll
    for (int n = 0; n < 8; ++n){ accH[n] = (f32x4){0.f,0.f,0.f,0.f}; accT[n] = (f32x4){0.f,0.f,0.f,0.f}; }
    #pragma unroll
    for (int kk = 0; kk < 4; ++kk){
        int arow = wv*16 + lr;
        unsigned int ab = ((unsigned int)(arow*256 + kk*64 + lg*16)) ^ ((unsigned int)(arow & 7) << 4);
        bf16x8 a = *(const bf16x8*)(smem + ab);
        #pragma unroll
        for (int n = 0; n < 8; ++n){
            int cc = n*16 + lr;
            unsigned int bb = ((unsigned int)(cc*256 + kk*64 + lg*16)) ^ ((unsigned int)(cc & 7) << 4);
            bf16x8 bh = *(const bf16x8*)(smem + 32768 + bb);
            bf16x8 bt = *(const bf16x8*)(smem + 65536 + bb);
            accH[n] = __builtin_amdgcn_mfma_f32_16x16x32_bf16(a, bh, accH[n], 0, 0, 0);
            accT[n] = __builtin_amdgcn_mfma_f32_16x16x32_bf16(a, bt, accT[n], 0, 0, 0);
        }
    }
    #pragma unroll
    for (int n = 0; n < 8; ++n){
        int cc = n*16 + lr;
        #pragma unroll
        for (int j = 0; j < 4; ++j){
            int mr = m0 + wv*16 + lg*4 + j;
            if (mr < N){
                H[(size_t)mr*CH + cc] = f2bf(accH[n][j]);
                T[(size_t)mr*CH + cc] = f2bf(accT[n][j]);
            }
        }
    }
}

// ---------------------------------------------------------------------------
// k2p: persistent pipelined main pass. BM=64, 256 thr (4 waves), ~20 tiles/blk.
//   LDS: B 32K (staged once) | A 16K | U 16K | red 1K = 65K, 2 blocks/CU.
//   Per tile: issue t+G loads -> stage t from regs (counted vmcnt, t+G stays
//   in flight) -> lgkm barrier -> MFMA/res/epilogue/frag-linear store -> bar.
//   Static 2-set unroll; stats in regs, one flush per block.
// ---------------------------------------------------------------------------
struct TileRegs {
    float4 eav[8];
    uint4  hv[4], tv[4];
};

__device__ __forceinline__ void issue_tile(TileRegs& R,
        const float* __restrict__ ea, const int* __restrict__ eidx,
        const unsigned short* __restrict__ Hm, const unsigned short* __restrict__ Tm,
        int tid, int E, int t){
    const size_t e0 = (size_t)t * BM;
    const int rb = tid >> 4, c = tid & 15;
    int ri[4], ci[4];
    #pragma unroll
    for (int i = 0; i < 4; ++i){
        ri[i] = eidx[e0 + rb + i*16];
        ci[i] = eidx[E + e0 + rb + i*16];
    }
    __builtin_amdgcn_sched_barrier(0);
    #pragma unroll
    for (int i = 0; i < 8; ++i){
        int g = tid + i*256;
        R.eav[i] = *(const float4*)(ea + (e0 + (g >> 5))*CH + (g & 31)*4);
    }
    __builtin_amdgcn_sched_barrier(0);
    #pragma unroll
    for (int i = 0; i < 4; ++i){
        R.hv[i] = *(const uint4*)(Hm + (size_t)ri[i]*CH + c*8);
        R.tv[i] = *(const uint4*)(Tm + (size_t)ci[i]*CH + c*8);
    }
    __builtin_amdgcn_sched_barrier(0);
}

__device__ __forceinline__ void stage_tile(const TileRegs& R,
        unsigned char* smem, int tid){
    #pragma unroll
    for (int i = 0; i < 8; ++i){
        int g = tid + i*256;
        int row = g >> 5, col4 = (g & 31)*4;
        float4 v = R.eav[i];
        unsigned int lo = (unsigned int)f2bf(v.x) | ((unsigned int)f2bf(v.y) << 16);
        unsigned int hi = (unsigned int)f2bf(v.z) | ((unsigned int)f2bf(v.w) << 16);
        unsigned int b = ((unsigned int)(row*256 + col4*2)) ^ ((unsigned int)(row & 7) << 4);
        *(uint2*)(smem + 32768 + b) = make_uint2(lo, hi);
    }
    const int rb = tid >> 4, c = tid & 15;
    #pragma unroll
    for (int i = 0; i < 4; ++i){
        int r = rb + i*16;
        uint4 u4;
        u4.x = pairadd_bf(R.hv[i].x, R.tv[i].x);
        u4.y = pairadd_bf(R.hv[i].y, R.tv[i].y);
        u4.z = pairadd_bf(R.hv[i].z, R.tv[i].z);
        u4.w = pairadd_bf(R.hv[i].w, R.tv[i].w);
        unsigned int b = ((unsigned int)(r*256 + c*16)) ^ ((unsigned int)((r >> 2) & 3) << 5);
        *(uint4*)(smem + 49152 + b) = u4;
    }
}

__device__ __forceinline__ void compute_tile(unsigned char* smem,
        uint4* __restrict__ VB4, int t, int lane, int wv,
        float* s, float* ss){
    const int lr = lane & 15, lg = lane >> 4;
    f32x4 acc[8];
    #pragma unroll
    for (int n = 0; n < 8; ++n) acc[n] = (f32x4){0.f,0.f,0.f,0.f};
    #pragma unroll
    for (int kk = 0; kk < 4; ++kk){
        int arow = wv*16 + lr;
        unsigned int ab = ((unsigned int)(arow*256 + kk*64 + lg*16)) ^ ((unsigned int)(arow & 7) << 4);
        bf16x8 a = *(const bf16x8*)(smem + 32768 + ab);
        #pragma unroll
        for (int n = 0; n < 8; ++n){
            int cc = n*16 + lr;
            unsigned int bb = ((unsigned int)(cc*256 + kk*64 + lg*16)) ^ ((unsigned int)(cc & 7) << 4);
            bf16x8 bw = *(const bf16x8*)(smem + bb);
            acc[n] = __builtin_amdgcn_mfma_f32_16x16x32_bf16(a, bw, acc[n], 0, 0, 0);
        }
    }
    // epilogue: res from A-tile, u from U-tile, v -> frag-linear store
    #pragma unroll
    for (int n2 = 0; n2 < 4; ++n2){
        unsigned int ow[4];
        #pragma unroll
        for (int h = 0; h < 2; ++h){
            int nn = n2*2 + h;
            int cc = nn*16 + lr;
            unsigned int w0 = 0, w1 = 0;
            #pragma unroll
            for (int j = 0; j < 4; ++j){
                int ml = wv*16 + lg*4 + j;
                unsigned int br = ((unsigned int)(ml*256 + cc*2)) ^ ((unsigned int)(ml & 7) << 4);
                unsigned int bu = ((unsigned int)(ml*256 + cc*2)) ^ ((unsigned int)((ml >> 2) & 3) << 5);
                float r = bf2f(*(const unsigned short*)(smem + 32768 + br));
                float u = bf2f(*(const unsigned short*)(smem + 49152 + bu));
                float o0 = acc[nn][j];
                float v = fmaf(o0, 0.5f*u, o0) + r;   // o0*(1+0.5(h+t)) + ea
                s[nn] += v; ss[nn] += v*v;
                unsigned int bv = (unsigned int)f2bf(v);
                if (j < 2) w0 |= bv << (j*16);
                else       w1 |= bv << ((j-2)*16);
            }
            ow[h*2] = w0; ow[h*2+1] = w1;
        }
        uint4 o; o.x = ow[0]; o.y = ow[1]; o.z = ow[2]; o.w = ow[3];
        VB4[(((size_t)t*4 + wv)*4 + n2)*64 + lane] = o;   // coalesced 1KB/wave
    }
}

__global__ __launch_bounds__(256, 2) void k2p(
        const float* __restrict__ ea, const int* __restrict__ eidx,
        const unsigned short* __restrict__ wT,
        const unsigned short* __restrict__ Hm, const unsigned short* __restrict__ Tm,
        uint4* __restrict__ VB4, float* __restrict__ sums, int E, int nt){
    __shared__ __align__(16) unsigned char smem[66560];  // B 32K | A 16K | U 16K | red 1K
    float* red = (float*)(smem + 65536);
    const int tid = threadIdx.x;
    const int lane = tid & 63, wv = tid >> 6;
    const int t0 = blockIdx.x, G = gridDim.x;

    // prologue: stage B (w_self) once
    #pragma unroll
    for (int i = 0; i < 8; ++i){
        int g = tid + i*256;
        int n = g >> 4, k8 = (g & 15)*8;
        uint4 v = *(const uint4*)(wT + n*CH + k8);
        unsigned int b = ((unsigned int)(n*256 + k8*2)) ^ ((unsigned int)(n & 7) << 4);
        *(uint4*)(smem + b) = v;
    }
    red[tid] = 0.f;
    asm volatile("s_waitcnt lgkmcnt(0)\n\ts_barrier" ::: "memory");

    float s[8], ss[8];
    #pragma unroll
    for (int n = 0; n < 8; ++n){ s[n] = 0.f; ss[n] = 0.f; }

    if (t0 < nt){
        TileRegs RA, RB;
        issue_tile(RA, ea, eidx, Hm, Tm, tid, E, t0);
        for (int t = t0; t < nt; t += 2*G){
            int t1 = t + G, t2 = t + 2*G;
            if (t1 < nt) issue_tile(RB, ea, eidx, Hm, Tm, tid, E, t1);
            stage_tile(RA, smem, tid);
            asm volatile("s_waitcnt lgkmcnt(0)\n\ts_barrier" ::: "memory");
            compute_tile(smem, VB4, t, lane, wv, s, ss);
            asm volatile("s_waitcnt lgkmcnt(0)\n\ts_barrier" ::: "memory");
            if (t1 < nt){
                if (t2 < nt) issue_tile(RA, ea, eidx, Hm, Tm, tid, E, t2);
                stage_tile(RB, smem, tid);
                asm volatile("s_waitcnt lgkmcnt(0)\n\ts_barrier" ::: "memory");
                compute_tile(smem, VB4, t1, lane, wv, s, ss);
                asm volatile("s_waitcnt lgkmcnt(0)\n\ts_barrier" ::: "memory");
            }
        }
    }
    // stats flush: lanes l, l^16, l^32, l^48 share channel set {n*16 + (l&15)}
    const int lr = lane & 15;
    #pragma unroll
    for (int n = 0; n < 8; ++n){
        s[n]  += __shfl_xor(s[n], 16);  s[n]  += __shfl_xor(s[n], 32);
        ss[n] += __shfl_xor(ss[n], 16); ss[n] += __shfl_xor(ss[n], 32);
    }
    if (lane < 16){
        #pragma unroll
        for (int n = 0; n < 8; ++n){
            atomicAdd(&red[n*16 + lr], s[n]);
            atomicAdd(&red[CH + n*16 + lr], ss[n]);
        }
    }
    __syncthreads();
    atomicAdd(&sums[(blockIdx.x & 255)*256 + tid], red[tid]);
}

// ---------------------------------------------------------------------------
// k3: reduce 256 slots -> per-channel scale/shift (sb)
// ---------------------------------------------------------------------------
__global__ __launch_bounds__(128) void k3_stats(
        const float* __restrict__ sums, const float* __restrict__ gamma,
        const float* __restrict__ beta, float* __restrict__ sb, float invE){
    int c = threadIdx.x;
    float s = 0.f, ss = 0.f;
    for (int i = 0; i < 256; ++i){ s += sums[i*256 + c]; ss += sums[i*256 + CH + c]; }
    float mean = s * invE;
    float var = ss * invE - mean*mean;     // biased variance (matches reference)
    float inv = rsqrtf(var + 1e-5f);
    float sc = gamma[c] * inv;
    sb[c] = sc;
    sb[CH + c] = beta[c] - mean * sc;
}

// ---------------------------------------------------------------------------
// kE1: decode fragment-linear VB4 (BM=64 tiles), BN+ReLU, f32 stores.
//   uint4 i: lane=i&63, n2=(i>>6)&3, wv=(i>>8)&3, tile=i>>10.
//   cols n2*32+lr (x,y) / +16 (z,w); rows tile*64 + wv*16 + lg*4 + j.
// ---------------------------------------------------------------------------
__global__ __launch_bounds__(256) void kE1(
        const uint4* __restrict__ VB4, const float* __restrict__ sb,
        float* __restrict__ out, int ntu){
    int i = blockIdx.x * 256 + threadIdx.x;
    int stride = gridDim.x * 256;
    for (; i < ntu; i += stride){
        uint4 v = VB4[i];
        int lane = i & 63, n2 = (i >> 6) & 3, wv = (i >> 8) & 3, tile = i >> 10;
        int lr = lane & 15, lg = lane >> 4;
        int colA = n2*32 + lr, colB = colA + 16;
        float scA = sb[colA], shA = sb[CH + colA];
        float scB = sb[colB], shB = sb[CH + colB];
        float* o = out + ((size_t)tile*64 + wv*16 + lg*4)*CH;
        o[0*CH + colA] = fmaxf(fmaf(bf2f((unsigned short)(v.x & 0xffff)), scA, shA), 0.f);
        o[1*CH + colA] = fmaxf(fmaf(bf2f((unsigned short)(v.x >> 16)),    scA, shA), 0.f);
        o[2*CH + colA] = fmaxf(fmaf(bf2f((unsigned short)(v.y & 0xffff)), scA, shA), 0.f);
        o[3*CH + colA] = fmaxf(fmaf(bf2f((unsigned short)(v.y >> 16)),    scA, shA), 0.f);
        o[0*CH + colB] = fmaxf(fmaf(bf2f((unsigned short)(v.z & 0xffff)), scB, shB), 0.f);
        o[1*CH + colB] = fmaxf(fmaf(bf2f((unsigned short)(v.z >> 16)),    scB, shB), 0.f);
        o[2*CH + colB] = fmaxf(fmaf(bf2f((unsigned short)(v.w & 0xffff)), scB, shB), 0.f);
        o[3*CH + colB] = fmaxf(fmaf(bf2f((unsigned short)(v.w >> 16)),    scB, shB), 0.f);
    }
}

extern "C" void kernel_launch(void* const* d_in, const int* in_sizes, int n_in,
                              void* d_out, int out_size, void* d_ws, size_t ws_size,
                              hipStream_t stream) {
    const float* x      = (const float*)d_in[0];
    const int*   eidx   = (const int*)d_in[1];
    const float* ea     = (const float*)d_in[2];
    const float* w_self = (const float*)d_in[4];
    const float* w_h    = (const float*)d_in[5];
    const float* w_t    = (const float*)d_in[6];
    const float* gamma  = (const float*)d_in[7];
    const float* beta   = (const float*)d_in[8];
    float* out = (float*)d_out;

    const int N = in_sizes[0] / CH;     // 40000
    const int E = in_sizes[3];          // 640000
    const int nt = E / BM;              // 10000 tiles

    // workspace carve-up (~185 MB total — proven to fit since R5):
    float* sums = (float*)d_ws;                          // 256*256 f32
    float* sb   = sums + 256*256;                        // 256 f32
    unsigned short* wT = (unsigned short*)(sb + 256);    // 3*128*128 bf16
    unsigned short* H  = wT + 3*CH*CH;                   // N*128 bf16
    unsigned short* T  = H + (size_t)N*CH;               // N*128 bf16
    uint4* VB4 = (uint4*)(T + (size_t)N*CH);             // E*128 bf16 (frag-linear)

    int G = nt < 512 ? nt : 512;

    k0_prep<<<256, 256, 0, stream>>>(w_self, w_h, w_t, wT, sums);
    k1_ht  <<<(N + 127)/128, 512, 0, stream>>>(x, wT, H, T, N);
    k2p    <<<G, 256, 0, stream>>>(ea, eidx, wT, H, T, VB4, sums, E, nt);
    k3_stats<<<1, 128, 0, stream>>>(sums, gamma, beta, sb, 1.0f/(float)E);
    kE1    <<<2048, 256, 0, stream>>>(VB4, sb, out, E*16);
}

// Round 12
// 360.311 us; speedup vs baseline: 1.8692x; 1.8692x over previous
//
#include <hip/hip_runtime.h>
#include <cstdint>
#include <cstddef>

#define CH 128

typedef __attribute__((ext_vector_type(8))) short bf16x8;
typedef __attribute__((ext_vector_type(4))) float f32x4;

__device__ __forceinline__ unsigned short f2bf(float x){
    unsigned int u = __float_as_uint(x);
    u = (u + 0x7FFFu + ((u >> 16) & 1u)) >> 16;   // RNE
    return (unsigned short)u;
}
__device__ __forceinline__ float bf2f(unsigned short b){
    return __uint_as_float(((unsigned int)b) << 16);
}

// ---------------------------------------------------------------------------
// k0: transpose+convert weights to bf16 wT[mat][n][k]; zero sums[256*256].
// ---------------------------------------------------------------------------
__global__ __launch_bounds__(256) void k0_prep(
        const float* __restrict__ w_self, const float* __restrict__ w_h,
        const float* __restrict__ w_t, unsigned short* __restrict__ wT,
        float* __restrict__ sums){
    int t = blockIdx.x * 256 + threadIdx.x;
    if (t < 256*256) sums[t] = 0.f;
    if (t < 3*CH*CH){
        int mat = t / (CH*CH);
        int r = t - mat*(CH*CH);
        int k = r >> 7, n = r & 127;
        const float* w = (mat == 0) ? w_self : ((mat == 1) ? w_h : w_t);
        wT[mat*CH*CH + n*CH + k] = f2bf(w[k*CH + n]);
    }
}

// ---------------------------------------------------------------------------
// k1: H = x @ w_h, T = x @ w_t  (bf16 out, f32 MFMA accumulate). Proven R0-R11.
// ---------------------------------------------------------------------------
__global__ __launch_bounds__(512) void k1_ht(
        const float* __restrict__ x, const unsigned short* __restrict__ wT,
        unsigned short* __restrict__ H, unsigned short* __restrict__ T, int N){
    __shared__ __align__(16) unsigned char smem[98304];
    const int tid = threadIdx.x;
    const int m0 = blockIdx.x * 128;
    #pragma unroll
    for (int i = 0; i < 8; ++i){
        int g = tid + i*512;
        int row = g >> 5, col4 = (g & 31) * 4;
        int rg = m0 + row; rg = rg < N ? rg : N-1;
        float4 v = *(const float4*)(x + (size_t)rg*CH + col4);
        unsigned int lo = (unsigned int)f2bf(v.x) | ((unsigned int)f2bf(v.y) << 16);
        unsigned int hi = (unsigned int)f2bf(v.z) | ((unsigned int)f2bf(v.w) << 16);
        unsigned int b = ((unsigned int)(row*256 + col4*2)) ^ ((unsigned int)(row & 7) << 4);
        *(uint2*)(smem + b) = make_uint2(lo, hi);
    }
    #pragma unroll
    for (int m = 0; m < 2; ++m){
        const unsigned short* src = wT + (m+1)*CH*CH;
        unsigned char* dst = smem + 32768 + m*32768;
        #pragma unroll
        for (int i = 0; i < 4; ++i){
            int g = tid + i*512;
            int n = g >> 4, k8 = (g & 15) * 8;
            uint4 v = *(const uint4*)(src + n*CH + k8);
            unsigned int b = ((unsigned int)(n*256 + k8*2)) ^ ((unsigned int)(n & 7) << 4);
            *(uint4*)(dst + b) = v;
        }
    }
    __syncthreads();
    const int lane = tid & 63, wv = tid >> 6;
    const int lr = lane & 15, lg = lane >> 4;
    f32x4 accH[8], accT[8];
    #pragma unroll
    for (int n = 0; n < 8; ++n){ accH[n] = (f32x4){0.f,0.f,0.f,0.f}; accT[n] = (f32x4){0.f,0.f,0.f,0.f}; }
    #pragma unroll
    for (int kk = 0; kk < 4; ++kk){
        int arow = wv*16 + lr;
        unsigned int ab = ((unsigned int)(arow*256 + kk*64 + lg*16)) ^ ((unsigned int)(arow & 7) << 4);
        bf16x8 a = *(const bf16x8*)(smem + ab);
        #pragma unroll
        for (int n = 0; n < 8; ++n){
            int cc = n*16 + lr;
            unsigned int bb = ((unsigned int)(cc*256 + kk*64 + lg*16)) ^ ((unsigned int)(cc & 7) << 4);
            bf16x8 bh = *(const bf16x8*)(smem + 32768 + bb);
            bf16x8 bt = *(const bf16x8*)(smem + 65536 + bb);
            accH[n] = __builtin_amdgcn_mfma_f32_16x16x32_bf16(a, bh, accH[n], 0, 0, 0);
            accT[n] = __builtin_amdgcn_mfma_f32_16x16x32_bf16(a, bt, accT[n], 0, 0, 0);
        }
    }
    #pragma unroll
    for (int n = 0; n < 8; ++n){
        int cc = n*16 + lr;
        #pragma unroll
        for (int j = 0; j < 4; ++j){
            int mr = m0 + wv*16 + lg*4 + j;
            if (mr < N){
                H[(size_t)mr*CH + cc] = f2bf(accH[n][j]);
                T[(size_t)mr*CH + cc] = f2bf(accT[n][j]);
            }
        }
    }
}

// ---------------------------------------------------------------------------
// k2v: R9's winning kernel, ONE change: __launch_bounds__(512, 2).
//   LDS (66.5KB) caps residency at 2 blocks/CU anyway; (512,4)'s 64-VGPR
//   cap forced phase serialization. 128 VGPRs let eav + gathers + staging
//   genuinely overlap per the sched_barrier-pinned issue order.
// ---------------------------------------------------------------------------
__global__ __launch_bounds__(512, 2) void k2v(
        const float* __restrict__ ea, const int* __restrict__ eidx,
        const unsigned short* __restrict__ wT,
        const unsigned short* __restrict__ Hm, const unsigned short* __restrict__ Tm,
        unsigned short* __restrict__ VB, float* __restrict__ sums, int E){
    __shared__ __align__(16) unsigned char smem[66560];
    float* red = (float*)(smem + 65536);
    const int tid = threadIdx.x;
    const int e0 = blockIdx.x * 128;
    if (tid < 256) red[tid] = 0.f;

    // ---- phase 0: edge-index loads (gather addresses depend on these) ----
    int ri4[4], ci4[4];
    #pragma unroll
    for (int i = 0; i < 4; ++i){
        int r = (tid + i*512) >> 4;
        ri4[i] = eidx[e0 + r];
        ci4[i] = eidx[E + e0 + r];
    }
    __builtin_amdgcn_sched_barrier(0);
    // ---- phase 1: weight tile loads (L2-hot) ----
    uint4 wv4[4];
    #pragma unroll
    for (int i = 0; i < 4; ++i){
        int g = tid + i*512;
        int n = g >> 4, k8 = (g & 15)*8;
        wv4[i] = *(const uint4*)(wT + n*CH + k8);
    }
    __builtin_amdgcn_sched_barrier(0);
    // ---- phase 2: streaming ea loads (HBM, hidden under later phases) ----
    float4 eav[8];
    #pragma unroll
    for (int i = 0; i < 8; ++i){
        int g = tid + i*512;
        int row = g >> 5, col4 = (g & 31)*4;
        eav[i] = *(const float4*)(ea + (size_t)(e0+row)*CH + col4);
    }
    __builtin_amdgcn_sched_barrier(0);
    // ---- phase 3: issue H/T gathers (waits only eidx: in-order vmcnt) ----
    uint4 hv[4], tv[4];
    #pragma unroll
    for (int i = 0; i < 4; ++i){
        int c = (tid + i*512) & 15;
        hv[i] = *(const uint4*)(Hm + (size_t)ri4[i]*CH + c*8);
        tv[i] = *(const uint4*)(Tm + (size_t)ci4[i]*CH + c*8);
    }
    __builtin_amdgcn_sched_barrier(0);
    // ---- phase 4: wv4 -> B LDS (wv4 regs die; eav+gathers stay in flight) --
    #pragma unroll
    for (int i = 0; i < 4; ++i){
        int g = tid + i*512;
        int n = g >> 4, k8 = (g & 15)*8;
        unsigned int b = ((unsigned int)(n*256 + k8*2)) ^ ((unsigned int)(n & 7) << 4);
        *(uint4*)(smem + 32768 + b) = wv4[i];
    }
    __builtin_amdgcn_sched_barrier(0);
    // ---- phase 5: stage ea -> bf16 A LDS (gathers stay out) ----
    #pragma unroll
    for (int i = 0; i < 8; ++i){
        int g = tid + i*512;
        int row = g >> 5, col4 = (g & 31)*4;
        float4 v = eav[i];
        unsigned int lo = (unsigned int)f2bf(v.x) | ((unsigned int)f2bf(v.y) << 16);
        unsigned int hi = (unsigned int)f2bf(v.z) | ((unsigned int)f2bf(v.w) << 16);
        unsigned int b = ((unsigned int)(row*256 + col4*2)) ^ ((unsigned int)(row & 7) << 4);
        *(uint2*)(smem + b) = make_uint2(lo, hi);
    }
    // B1: LDS-only barrier (gathers NOT drained)
    asm volatile("s_waitcnt lgkmcnt(0)\n\ts_barrier" ::: "memory");

    const int lane = tid & 63, wv = tid >> 6;
    const int lr = lane & 15, lg = lane >> 4;
    f32x4 acc[8];
    #pragma unroll
    for (int n = 0; n < 8; ++n) acc[n] = (f32x4){0.f,0.f,0.f,0.f};
    #pragma unroll
    for (int kk = 0; kk < 4; ++kk){
        int arow = wv*16 + lr;
        unsigned int ab = ((unsigned int)(arow*256 + kk*64 + lg*16)) ^ ((unsigned int)(arow & 7) << 4);
        bf16x8 a = *(const bf16x8*)(smem + ab);
        #pragma unroll
        for (int n = 0; n < 8; ++n){
            int cc = n*16 + lr;
            unsigned int bb = ((unsigned int)(cc*256 + kk*64 + lg*16)) ^ ((unsigned int)(cc & 7) << 4);
            bf16x8 bw = *(const bf16x8*)(smem + 32768 + bb);
            acc[n] = __builtin_amdgcn_mfma_f32_16x16x32_bf16(a, bw, acc[n], 0, 0, 0);
        }
    }
    // ---- residual: read staged ea (bf16) before overwrite ----
    float res[32];
    #pragma unroll
    for (int n = 0; n < 8; ++n){
        int cc = n*16 + lr;
        #pragma unroll
        for (int j = 0; j < 4; ++j){
            int ml = wv*16 + lg*4 + j;
            unsigned int b = ((unsigned int)(ml*256 + cc*2)) ^ ((unsigned int)(ml & 7) << 4);
            res[n*4 + j] = bf2f(*(const unsigned short*)(smem + b));
        }
    }
    asm volatile("s_waitcnt lgkmcnt(0)\n\ts_barrier" ::: "memory");   // B2
    // ---- redistribute gathers (vmcnt waits hv/tv HERE) ----
    #pragma unroll
    for (int i = 0; i < 4; ++i){
        int g = tid + i*512;
        int r = g >> 4, c = g & 15;
        unsigned int b = ((unsigned int)(r*256 + c*16)) ^ ((unsigned int)((r >> 2) & 3) << 5);
        *(uint4*)(smem + b) = hv[i];
        *(uint4*)(smem + 32768 + b) = tv[i];
    }
    asm volatile("s_waitcnt lgkmcnt(0)\n\ts_barrier" ::: "memory");   // B3
    // ---- epilogue: v = o0*(1+0.5(h+t)) + res; stats; bf16 v in-place ----
    #pragma unroll
    for (int n = 0; n < 8; ++n){
        int cc = n*16 + lr;
        float s = 0.f, ss = 0.f;
        #pragma unroll
        for (int j = 0; j < 4; ++j){
            int ml = wv*16 + lg*4 + j;
            unsigned int b = ((unsigned int)(ml*256 + cc*2)) ^ ((unsigned int)((ml >> 2) & 3) << 5);
            float h = bf2f(*(const unsigned short*)(smem + b));
            float t = bf2f(*(const unsigned short*)(smem + 32768 + b));
            float v = acc[n][j] * (1.f + 0.5f*(h + t)) + res[n*4 + j];
            *(unsigned short*)(smem + b) = f2bf(v);   // single reader=writer
            s += v; ss += v*v;
        }
        s  += __shfl_xor(s, 16);  s  += __shfl_xor(s, 32);
        ss += __shfl_xor(ss, 16); ss += __shfl_xor(ss, 32);
        if (lane < 16){
            atomicAdd(&red[cc], s);
            atomicAdd(&red[CH + cc], ss);
        }
    }
    asm volatile("s_waitcnt lgkmcnt(0)\n\ts_barrier" ::: "memory");   // B4
    // ---- coalesced readback + 16B stores of bf16 VB ----
    #pragma unroll
    for (int i = 0; i < 4; ++i){
        int g = tid + i*512;
        int r = g >> 4, c16 = g & 15;
        unsigned int b = ((unsigned int)(r*256 + c16*16)) ^ ((unsigned int)((r >> 2) & 3) << 5);
        uint4 o = *(const uint4*)(smem + b);
        *(uint4*)(VB + (size_t)(e0 + r)*CH + c16*8) = o;
    }
    if (tid < 256) atomicAdd(&sums[(blockIdx.x & 255)*256 + tid], red[tid]);
}

// ---------------------------------------------------------------------------
// k3: reduce 256 slots -> per-channel scale/shift (sb)
// ---------------------------------------------------------------------------
__global__ __launch_bounds__(128) void k3_stats(
        const float* __restrict__ sums, const float* __restrict__ gamma,
        const float* __restrict__ beta, float* __restrict__ sb, float invE){
    int c = threadIdx.x;
    float s = 0.f, ss = 0.f;
    for (int i = 0; i < 256; ++i){ s += sums[i*256 + c]; ss += sums[i*256 + CH + c]; }
    float mean = s * invE;
    float var = ss * invE - mean*mean;     // biased variance (matches reference)
    float inv = rsqrtf(var + 1e-5f);
    float sc = gamma[c] * inv;
    sb[c] = sc;
    sb[CH + c] = beta[c] - mean * sc;
}

// ---------------------------------------------------------------------------
// kE1: out_f32 = relu(vb*scale + shift); 8 elems/thread (proven ~90us)
// ---------------------------------------------------------------------------
__global__ __launch_bounds__(256) void kE1(
        const unsigned short* __restrict__ vb, const float* __restrict__ sb,
        float* __restrict__ out, int n8){
    int i = blockIdx.x * 256 + threadIdx.x;
    int stride = gridDim.x * 256;
    const uint4* v8 = (const uint4*)vb;
    for (; i < n8; i += stride){
        uint4 v = v8[i];
        int c8 = (i & 15) * 8;
        float4 sc0 = *(const float4*)(sb + c8);
        float4 sc1 = *(const float4*)(sb + c8 + 4);
        float4 sh0 = *(const float4*)(sb + CH + c8);
        float4 sh1 = *(const float4*)(sb + CH + c8 + 4);
        float4 o0, o1;
        o0.x = fmaxf(fmaf(bf2f((unsigned short)(v.x & 0xffff)), sc0.x, sh0.x), 0.f);
        o0.y = fmaxf(fmaf(bf2f((unsigned short)(v.x >> 16)),    sc0.y, sh0.y), 0.f);
        o0.z = fmaxf(fmaf(bf2f((unsigned short)(v.y & 0xffff)), sc0.z, sh0.z), 0.f);
        o0.w = fmaxf(fmaf(bf2f((unsigned short)(v.y >> 16)),    sc0.w, sh0.w), 0.f);
        o1.x = fmaxf(fmaf(bf2f((unsigned short)(v.z & 0xffff)), sc1.x, sh1.x), 0.f);
        o1.y = fmaxf(fmaf(bf2f((unsigned short)(v.z >> 16)),    sc1.y, sh1.y), 0.f);
        o1.z = fmaxf(fmaf(bf2f((unsigned short)(v.w & 0xffff)), sc1.z, sh1.z), 0.f);
        o1.w = fmaxf(fmaf(bf2f((unsigned short)(v.w >> 16)),    sc1.w, sh1.w), 0.f);
        *(float4*)(out + (size_t)i*8)     = o0;
        *(float4*)(out + (size_t)i*8 + 4) = o1;
    }
}

extern "C" void kernel_launch(void* const* d_in, const int* in_sizes, int n_in,
                              void* d_out, int out_size, void* d_ws, size_t ws_size,
                              hipStream_t stream) {
    const float* x      = (const float*)d_in[0];
    const int*   eidx   = (const int*)d_in[1];
    const float* ea     = (const float*)d_in[2];
    const float* w_self = (const float*)d_in[4];
    const float* w_h    = (const float*)d_in[5];
    const float* w_t    = (const float*)d_in[6];
    const float* gamma  = (const float*)d_in[7];
    const float* beta   = (const float*)d_in[8];
    float* out = (float*)d_out;

    const int N = in_sizes[0] / CH;     // 40000
    const int E = in_sizes[3];          // 640000

    // workspace carve-up (~185 MB total — proven to fit since R5):
    float* sums = (float*)d_ws;                          // 256*256 f32
    float* sb   = sums + 256*256;                        // 256 f32
    unsigned short* wT = (unsigned short*)(sb + 256);    // 3*128*128 bf16
    unsigned short* H  = wT + 3*CH*CH;                   // N*128 bf16
    unsigned short* T  = H + (size_t)N*CH;               // N*128 bf16
    unsigned short* VB = T + (size_t)N*CH;               // E*128 bf16 pre-BN

    k0_prep<<<256, 256, 0, stream>>>(w_self, w_h, w_t, wT, sums);
    k1_ht  <<<(N + 127)/128, 512, 0, stream>>>(x, wT, H, T, N);
    k2v    <<<E/128, 512, 0, stream>>>(ea, eidx, wT, H, T, VB, sums, E);
    k3_stats<<<1, 128, 0, stream>>>(sums, gamma, beta, sb, 1.0f/(float)E);
    kE1    <<<2048, 256, 0, stream>>>(VB, sb, out, E*CH/8);
}

// Round 13
// 301.162 us; speedup vs baseline: 2.2363x; 1.1964x over previous
//
#include <hip/hip_runtime.h>
#include <cstdint>
#include <cstddef>

#define CH 128

typedef __attribute__((ext_vector_type(8))) short bf16x8;
typedef __attribute__((ext_vector_type(4))) float f32x4;

__device__ __forceinline__ unsigned short f2bf(float x){
    unsigned int u = __float_as_uint(x);
    u = (u + 0x7FFFu + ((u >> 16) & 1u)) >> 16;   // RNE
    return (unsigned short)u;
}
__device__ __forceinline__ float bf2f(unsigned short b){
    return __uint_as_float(((unsigned int)b) << 16);
}
__device__ __forceinline__ unsigned int pairadd_bf(unsigned int a, unsigned int b){
    float lo = bf2f((unsigned short)(a & 0xffff)) + bf2f((unsigned short)(b & 0xffff));
    float hi = bf2f((unsigned short)(a >> 16))    + bf2f((unsigned short)(b >> 16));
    return (unsigned int)f2bf(lo) | ((unsigned int)f2bf(hi) << 16);
}

// ---------------------------------------------------------------------------
// k0: transpose+convert weights to bf16 wT[mat][n][k]; zero sums[256*256].
// ---------------------------------------------------------------------------
__global__ __launch_bounds__(256) void k0_prep(
        const float* __restrict__ w_self, const float* __restrict__ w_h,
        const float* __restrict__ w_t, unsigned short* __restrict__ wT,
        float* __restrict__ sums){
    int t = blockIdx.x * 256 + threadIdx.x;
    if (t < 256*256) sums[t] = 0.f;
    if (t < 3*CH*CH){
        int mat = t / (CH*CH);
        int r = t - mat*(CH*CH);
        int k = r >> 7, n = r & 127;
        const float* w = (mat == 0) ? w_self : ((mat == 1) ? w_h : w_t);
        wT[mat*CH*CH + n*CH + k] = f2bf(w[k*CH + n]);
    }
}

// ---------------------------------------------------------------------------
// k1: H = x @ w_h, T = x @ w_t  (bf16 out, f32 MFMA accumulate). Proven R0-R12.
// ---------------------------------------------------------------------------
__global__ __launch_bounds__(512) void k1_ht(
        const float* __restrict__ x, const unsigned short* __restrict__ wT,
        unsigned short* __restrict__ H, unsigned short* __restrict__ T, int N){
    __shared__ __align__(16) unsigned char smem[98304];
    const int tid = threadIdx.x;
    const int m0 = blockIdx.x * 128;
    #pragma unroll
    for (int i = 0; i < 8; ++i){
        int g = tid + i*512;
        int row = g >> 5, col4 = (g & 31) * 4;
        int rg = m0 + row; rg = rg < N ? rg : N-1;
        float4 v = *(const float4*)(x + (size_t)rg*CH + col4);
        unsigned int lo = (unsigned int)f2bf(v.x) | ((unsigned int)f2bf(v.y) << 16);
        unsigned int hi = (unsigned int)f2bf(v.z) | ((unsigned int)f2bf(v.w) << 16);
        unsigned int b = ((unsigned int)(row*256 + col4*2)) ^ ((unsigned int)(row & 7) << 4);
        *(uint2*)(smem + b) = make_uint2(lo, hi);
    }
    #pragma unroll
    for (int m = 0; m < 2; ++m){
        const unsigned short* src = wT + (m+1)*CH*CH;
        unsigned char* dst = smem + 32768 + m*32768;
        #pragma unroll
        for (int i = 0; i < 4; ++i){
            int g = tid + i*512;
            int n = g >> 4, k8 = (g & 15) * 8;
            uint4 v = *(const uint4*)(src + n*CH + k8);
            unsigned int b = ((unsigned int)(n*256 + k8*2)) ^ ((unsigned int)(n & 7) << 4);
            *(uint4*)(dst + b) = v;
        }
    }
    __syncthreads();
    const int lane = tid & 63, wv = tid >> 6;
    const int lr = lane & 15, lg = lane >> 4;
    f32x4 accH[8], accT[8];
    #pragma unroll
    for (int n = 0; n < 8; ++n){ accH[n] = (f32x4){0.f,0.f,0.f,0.f}; accT[n] = (f32x4){0.f,0.f,0.f,0.f}; }
    #pragma unroll
    for (int kk = 0; kk < 4; ++kk){
        int arow = wv*16 + lr;
        unsigned int ab = ((unsigned int)(arow*256 + kk*64 + lg*16)) ^ ((unsigned int)(arow & 7) << 4);
        bf16x8 a = *(const bf16x8*)(smem + ab);
        #pragma unroll
        for (int n = 0; n < 8; ++n){
            int cc = n*16 + lr;
            unsigned int bb = ((unsigned int)(cc*256 + kk*64 + lg*16)) ^ ((unsigned int)(cc & 7) << 4);
            bf16x8 bh = *(const bf16x8*)(smem + 32768 + bb);
            bf16x8 bt = *(const bf16x8*)(smem + 65536 + bb);
            accH[n] = __builtin_amdgcn_mfma_f32_16x16x32_bf16(a, bh, accH[n], 0, 0, 0);
            accT[n] = __builtin_amdgcn_mfma_f32_16x16x32_bf16(a, bt, accT[n], 0, 0, 0);
        }
    }
    #pragma unroll
    for (int n = 0; n < 8; ++n){
        int cc = n*16 + lr;
        #pragma unroll
        for (int j = 0; j < 4; ++j){
            int mr = m0 + wv*16 + lg*4 + j;
            if (mr < N){
                H[(size_t)mr*CH + cc] = f2bf(accH[n][j]);
                T[(size_t)mr*CH + cc] = f2bf(accT[n][j]);
            }
        }
    }
}

// ---------------------------------------------------------------------------
// k2v v4: R12's winning structure + R10's two proven LDS cuts:
//   (1) u = h+t pre-added at redistribute (one 32K u-tile in dead B region)
//   (2) fragment-linear VB4 store straight from regs (no v LDS round-trip)
//   LDS u16 ops/thread 128->64, b128 60->52, barriers 4->3.
// ---------------------------------------------------------------------------
__global__ __launch_bounds__(512, 2) void k2v(
        const float* __restrict__ ea, const int* __restrict__ eidx,
        const unsigned short* __restrict__ wT,
        const unsigned short* __restrict__ Hm, const unsigned short* __restrict__ Tm,
        uint4* __restrict__ VB4, float* __restrict__ sums, int E){
    __shared__ __align__(16) unsigned char smem[66560];   // A 32K | B->U 32K | red 1K
    float* red = (float*)(smem + 65536);
    const int tid = threadIdx.x;
    const int e0 = blockIdx.x * 128;
    if (tid < 256) red[tid] = 0.f;

    // ---- phase 0: edge-index loads ----
    int ri4[4], ci4[4];
    #pragma unroll
    for (int i = 0; i < 4; ++i){
        int r = (tid + i*512) >> 4;
        ri4[i] = eidx[e0 + r];
        ci4[i] = eidx[E + e0 + r];
    }
    __builtin_amdgcn_sched_barrier(0);
    // ---- phase 1: weight tile loads (L2-hot) ----
    uint4 wv4[4];
    #pragma unroll
    for (int i = 0; i < 4; ++i){
        int g = tid + i*512;
        int n = g >> 4, k8 = (g & 15)*8;
        wv4[i] = *(const uint4*)(wT + n*CH + k8);
    }
    __builtin_amdgcn_sched_barrier(0);
    // ---- phase 2: streaming ea loads ----
    float4 eav[8];
    #pragma unroll
    for (int i = 0; i < 8; ++i){
        int g = tid + i*512;
        int row = g >> 5, col4 = (g & 31)*4;
        eav[i] = *(const float4*)(ea + (size_t)(e0+row)*CH + col4);
    }
    __builtin_amdgcn_sched_barrier(0);
    // ---- phase 3: issue H/T gathers (vmcnt waits only eidx) ----
    uint4 hv[4], tv[4];
    #pragma unroll
    for (int i = 0; i < 4; ++i){
        int c = (tid + i*512) & 15;
        hv[i] = *(const uint4*)(Hm + (size_t)ri4[i]*CH + c*8);
        tv[i] = *(const uint4*)(Tm + (size_t)ci4[i]*CH + c*8);
    }
    __builtin_amdgcn_sched_barrier(0);
    // ---- phase 4: wv4 -> B LDS (wv4 dies; eav+gathers stay in flight) ----
    #pragma unroll
    for (int i = 0; i < 4; ++i){
        int g = tid + i*512;
        int n = g >> 4, k8 = (g & 15)*8;
        unsigned int b = ((unsigned int)(n*256 + k8*2)) ^ ((unsigned int)(n & 7) << 4);
        *(uint4*)(smem + 32768 + b) = wv4[i];
    }
    __builtin_amdgcn_sched_barrier(0);
    // ---- phase 5: stage ea -> bf16 A LDS (gathers stay out) ----
    #pragma unroll
    for (int i = 0; i < 8; ++i){
        int g = tid + i*512;
        int row = g >> 5, col4 = (g & 31)*4;
        float4 v = eav[i];
        unsigned int lo = (unsigned int)f2bf(v.x) | ((unsigned int)f2bf(v.y) << 16);
        unsigned int hi = (unsigned int)f2bf(v.z) | ((unsigned int)f2bf(v.w) << 16);
        unsigned int b = ((unsigned int)(row*256 + col4*2)) ^ ((unsigned int)(row & 7) << 4);
        *(uint2*)(smem + b) = make_uint2(lo, hi);
    }
    // B1: LDS-only barrier (gathers NOT drained)
    asm volatile("s_waitcnt lgkmcnt(0)\n\ts_barrier" ::: "memory");

    const int lane = tid & 63, wv = tid >> 6;
    const int lr = lane & 15, lg = lane >> 4;
    f32x4 acc[8];
    #pragma unroll
    for (int n = 0; n < 8; ++n) acc[n] = (f32x4){0.f,0.f,0.f,0.f};
    #pragma unroll
    for (int kk = 0; kk < 4; ++kk){
        int arow = wv*16 + lr;
        unsigned int ab = ((unsigned int)(arow*256 + kk*64 + lg*16)) ^ ((unsigned int)(arow & 7) << 4);
        bf16x8 a = *(const bf16x8*)(smem + ab);
        #pragma unroll
        for (int n = 0; n < 8; ++n){
            int cc = n*16 + lr;
            unsigned int bb = ((unsigned int)(cc*256 + kk*64 + lg*16)) ^ ((unsigned int)(cc & 7) << 4);
            bf16x8 bw = *(const bf16x8*)(smem + 32768 + bb);
            acc[n] = __builtin_amdgcn_mfma_f32_16x16x32_bf16(a, bw, acc[n], 0, 0, 0);
        }
    }
    // ---- residual: read staged ea (bf16) ----
    float res[32];
    #pragma unroll
    for (int n = 0; n < 8; ++n){
        int cc = n*16 + lr;
        #pragma unroll
        for (int j = 0; j < 4; ++j){
            int ml = wv*16 + lg*4 + j;
            unsigned int b = ((unsigned int)(ml*256 + cc*2)) ^ ((unsigned int)(ml & 7) << 4);
            res[n*4 + j] = bf2f(*(const unsigned short*)(smem + b));
        }
    }
    asm volatile("s_waitcnt lgkmcnt(0)\n\ts_barrier" ::: "memory");   // B2: B region free
    // ---- redistribute: u = h+t -> u-tile (B region), 4 b128 writes ----
    #pragma unroll
    for (int i = 0; i < 4; ++i){
        int g = tid + i*512;
        int r = g >> 4, c = g & 15;
        uint4 u4;
        u4.x = pairadd_bf(hv[i].x, tv[i].x);
        u4.y = pairadd_bf(hv[i].y, tv[i].y);
        u4.z = pairadd_bf(hv[i].z, tv[i].z);
        u4.w = pairadd_bf(hv[i].w, tv[i].w);
        unsigned int b = ((unsigned int)(r*256 + c*16)) ^ ((unsigned int)((r >> 2) & 3) << 5);
        *(uint4*)(smem + 32768 + b) = u4;
    }
    asm volatile("s_waitcnt lgkmcnt(0)\n\ts_barrier" ::: "memory");   // B3: u visible
    // ---- epilogue: v = o0*(1+0.5u) + res; stats; frag-linear VB4 store ----
    #pragma unroll
    for (int n2 = 0; n2 < 4; ++n2){
        unsigned int ow[4];
        #pragma unroll
        for (int h = 0; h < 2; ++h){
            int nn = n2*2 + h;
            int cc = nn*16 + lr;
            float s = 0.f, ss = 0.f;
            unsigned int w0 = 0, w1 = 0;
            #pragma unroll
            for (int j = 0; j < 4; ++j){
                int ml = wv*16 + lg*4 + j;
                unsigned int b = ((unsigned int)(ml*256 + cc*2)) ^ ((unsigned int)((ml >> 2) & 3) << 5);
                float u = bf2f(*(const unsigned short*)(smem + 32768 + b));
                float o0 = acc[nn][j];
                float v = fmaf(o0, 0.5f*u, o0) + res[nn*4 + j];
                s += v; ss += v*v;
                unsigned int bv = (unsigned int)f2bf(v);
                if (j < 2) w0 |= bv << (j*16);
                else       w1 |= bv << ((j-2)*16);
            }
            ow[h*2] = w0; ow[h*2+1] = w1;
            s  += __shfl_xor(s, 16);  s  += __shfl_xor(s, 32);
            ss += __shfl_xor(ss, 16); ss += __shfl_xor(ss, 32);
            if (lane < 16){
                atomicAdd(&red[cc], s);
                atomicAdd(&red[CH + cc], ss);
            }
        }
        uint4 o; o.x = ow[0]; o.y = ow[1]; o.z = ow[2]; o.w = ow[3];
        VB4[((size_t)(blockIdx.x*8 + wv)*4 + n2)*64 + lane] = o;   // coalesced 1KB/wave
    }
    asm volatile("s_waitcnt lgkmcnt(0)\n\ts_barrier" ::: "memory");   // red complete
    if (tid < 256) atomicAdd(&sums[(blockIdx.x & 255)*256 + tid], red[tid]);
}

// ---------------------------------------------------------------------------
// k3: reduce 256 slots -> per-channel scale/shift (sb)
// ---------------------------------------------------------------------------
__global__ __launch_bounds__(128) void k3_stats(
        const float* __restrict__ sums, const float* __restrict__ gamma,
        const float* __restrict__ beta, float* __restrict__ sb, float invE){
    int c = threadIdx.x;
    float s = 0.f, ss = 0.f;
    for (int i = 0; i < 256; ++i){ s += sums[i*256 + c]; ss += sums[i*256 + CH + c]; }
    float mean = s * invE;
    float var = ss * invE - mean*mean;     // biased variance (matches reference)
    float inv = rsqrtf(var + 1e-5f);
    float sc = gamma[c] * inv;
    sb[c] = sc;
    sb[CH + c] = beta[c] - mean * sc;
}

// ---------------------------------------------------------------------------
// kE1: decode fragment-linear VB4 (BM=128 tiles), BN+ReLU, 64B-segment stores.
//   uint4 i: lane=i&63, n2=(i>>6)&3, wv=(i>>8)&7, blk=i>>11.
//   cols n2*32+lr (x,y) / +16 (z,w); rows blk*128 + wv*16 + lg*4 + j.
// ---------------------------------------------------------------------------
__global__ __launch_bounds__(256) void kE1(
        const uint4* __restrict__ VB4, const float* __restrict__ sb,
        float* __restrict__ out, int nt){
    int i = blockIdx.x * 256 + threadIdx.x;
    int stride = gridDim.x * 256;
    for (; i < nt; i += stride){
        uint4 v = VB4[i];
        int lane = i & 63, n2 = (i >> 6) & 3, wv = (i >> 8) & 7, blk = i >> 11;
        int lr = lane & 15, lg = lane >> 4;
        int colA = n2*32 + lr, colB = colA + 16;
        float scA = sb[colA], shA = sb[CH + colA];
        float scB = sb[colB], shB = sb[CH + colB];
        float* o = out + ((size_t)blk*128 + wv*16 + lg*4)*CH;
        o[0*CH + colA] = fmaxf(fmaf(bf2f((unsigned short)(v.x & 0xffff)), scA, shA), 0.f);
        o[1*CH + colA] = fmaxf(fmaf(bf2f((unsigned short)(v.x >> 16)),    scA, shA), 0.f);
        o[2*CH + colA] = fmaxf(fmaf(bf2f((unsigned short)(v.y & 0xffff)), scA, shA), 0.f);
        o[3*CH + colA] = fmaxf(fmaf(bf2f((unsigned short)(v.y >> 16)),    scA, shA), 0.f);
        o[0*CH + colB] = fmaxf(fmaf(bf2f((unsigned short)(v.z & 0xffff)), scB, shB), 0.f);
        o[1*CH + colB] = fmaxf(fmaf(bf2f((unsigned short)(v.z >> 16)),    scB, shB), 0.f);
        o[2*CH + colB] = fmaxf(fmaf(bf2f((unsigned short)(v.w & 0xffff)), scB, shB), 0.f);
        o[3*CH + colB] = fmaxf(fmaf(bf2f((unsigned short)(v.w >> 16)),    scB, shB), 0.f);
    }
}

extern "C" void kernel_launch(void* const* d_in, const int* in_sizes, int n_in,
                              void* d_out, int out_size, void* d_ws, size_t ws_size,
                              hipStream_t stream) {
    const float* x      = (const float*)d_in[0];
    const int*   eidx   = (const int*)d_in[1];
    const float* ea     = (const float*)d_in[2];
    const float* w_self = (const float*)d_in[4];
    const float* w_h    = (const float*)d_in[5];
    const float* w_t    = (const float*)d_in[6];
    const float* gamma  = (const float*)d_in[7];
    const float* beta   = (const float*)d_in[8];
    float* out = (float*)d_out;

    const int N = in_sizes[0] / CH;     // 40000
    const int E = in_sizes[3];          // 640000

    // workspace carve-up (~185 MB total — proven to fit since R5):
    float* sums = (float*)d_ws;                          // 256*256 f32
    float* sb   = sums + 256*256;                        // 256 f32
    unsigned short* wT = (unsigned short*)(sb + 256);    // 3*128*128 bf16
    unsigned short* H  = wT + 3*CH*CH;                   // N*128 bf16
    unsigned short* T  = H + (size_t)N*CH;               // N*128 bf16
    uint4* VB4 = (uint4*)(T + (size_t)N*CH);             // E*128 bf16 (frag-linear)

    k0_prep<<<256, 256, 0, stream>>>(w_self, w_h, w_t, wT, sums);
    k1_ht  <<<(N + 127)/128, 512, 0, stream>>>(x, wT, H, T, N);
    k2v    <<<E/128, 512, 0, stream>>>(ea, eidx, wT, H, T, VB4, sums, E);
    k3_stats<<<1, 128, 0, stream>>>(sums, gamma, beta, sb, 1.0f/(float)E);
    kE1    <<<2048, 256, 0, stream>>>(VB4, sb, out, E*CH/8);
}